// Round 1
// 1143.478 us; speedup vs baseline: 1.6683x; 1.6683x over previous
//
#include <hip/hip_runtime.h>

// B=2, S=2048, D=1024, H=16, DK=64.
// Round 1: all GEMMs on MFMA via split-bf16 (hi/lo) 3-term products.
// C = A*B^T tiles: BM=BN=128 (ctx: BN=64), BK=32, 256 thr / 4 waves,
// wave tile 64x64 as 4x4 frags of mfma_f32_16x16x32_bf16.
// LDS rows padded to 40 bf16 (80B = 20 dwords, gcd(20,32)=4 -> <=2-way banks).

#define Bsz 2
#define Ssz 2048
#define Dsz 1024
#define Hsz 16
#define DKsz 64
#define Msz (Bsz * Ssz)   // 4096
#define BHsz (Bsz * Hsz)  // 32

typedef __attribute__((ext_vector_type(8))) short bf16x8;
typedef __attribute__((ext_vector_type(4))) short bf16x4;
typedef __attribute__((ext_vector_type(4))) float f32x4;

#define MFMA16(a, b, c) __builtin_amdgcn_mfma_f32_16x16x32_bf16((a), (b), (c), 0, 0, 0)

__device__ __forceinline__ short f2bf(float f) {
  unsigned u = __float_as_uint(f);
  u += 0x7fffu + ((u >> 16) & 1u);  // RNE
  return (short)(u >> 16);
}
__device__ __forceinline__ float bf2f(short b) {
  return __uint_as_float(((unsigned)(unsigned short)b) << 16);
}

// ---------------------------------------------------------------------------
// Kernel 1: QKV projection.  z = q/k/v.  Writes split-bf16 Q,K in [bh][s][dk]
// and V transposed [bh][dk][s].
// ---------------------------------------------------------------------------
__global__ __launch_bounds__(256, 2) void qkv_proj_k(
    const float* __restrict__ Xq, const float* __restrict__ Xk,
    const float* __restrict__ Xv, const float* __restrict__ Wq,
    const float* __restrict__ Wk, const float* __restrict__ Wv,
    short* __restrict__ Qh, short* __restrict__ Ql,
    short* __restrict__ Kh, short* __restrict__ Kl,
    short* __restrict__ Vth, short* __restrict__ Vtl) {
  const int z = blockIdx.z;
  const float* A = (z == 0) ? Xq : (z == 1) ? Xk : Xv;
  const float* W = (z == 0) ? Wq : (z == 1) ? Wk : Wv;

  __shared__ __align__(16) short Ah[128][40];
  __shared__ __align__(16) short Al[128][40];
  __shared__ __align__(16) short Bh[128][40];
  __shared__ __align__(16) short Bl[128][40];

  const int t = threadIdx.x;
  const int l = t & 63, wid = t >> 6;
  const int wm = (wid >> 1) * 64, wn = (wid & 1) * 64;
  const int lr = l & 15, kg = l >> 4;
  const int m0 = blockIdx.y * 128, n0 = blockIdx.x * 128;
  const int sr = t >> 3, sc = (t & 7) * 4;  // staging: 32 rows x (8thr*4col)

  f32x4 acc[4][4] = {};
  float4 av[4], bv[4];

  auto ldg = [&](int k0) {
#pragma unroll
    for (int i = 0; i < 4; ++i) {
      av[i] = *(const float4*)(A + (size_t)(m0 + sr + i * 32) * Dsz + k0 + sc);
      bv[i] = *(const float4*)(W + (size_t)(n0 + sr + i * 32) * Dsz + k0 + sc);
    }
  };
  auto sts = [&]() {
#pragma unroll
    for (int i = 0; i < 4; ++i) {
      bf16x4 ah, al4, bh, bl4;
      const float* pa = (const float*)&av[i];
      const float* pb = (const float*)&bv[i];
#pragma unroll
      for (int j = 0; j < 4; ++j) {
        float fa = pa[j];
        short ha = f2bf(fa);
        ah[j] = ha;
        al4[j] = f2bf(fa - bf2f(ha));
        float fb = pb[j];
        short hb = f2bf(fb);
        bh[j] = hb;
        bl4[j] = f2bf(fb - bf2f(hb));
      }
      *(bf16x4*)&Ah[sr + i * 32][sc] = ah;
      *(bf16x4*)&Al[sr + i * 32][sc] = al4;
      *(bf16x4*)&Bh[sr + i * 32][sc] = bh;
      *(bf16x4*)&Bl[sr + i * 32][sc] = bl4;
    }
  };
  auto mma = [&]() {
    bf16x8 aH[4], aL[4], bH[4], bL[4];
#pragma unroll
    for (int f = 0; f < 4; ++f) {
      aH[f] = *(const bf16x8*)&Ah[wm + f * 16 + lr][kg * 8];
      aL[f] = *(const bf16x8*)&Al[wm + f * 16 + lr][kg * 8];
      bH[f] = *(const bf16x8*)&Bh[wn + f * 16 + lr][kg * 8];
      bL[f] = *(const bf16x8*)&Bl[wn + f * 16 + lr][kg * 8];
    }
#pragma unroll
    for (int fi = 0; fi < 4; ++fi)
#pragma unroll
      for (int fj = 0; fj < 4; ++fj) {
        acc[fi][fj] = MFMA16(aH[fi], bH[fj], acc[fi][fj]);
        acc[fi][fj] = MFMA16(aH[fi], bL[fj], acc[fi][fj]);
        acc[fi][fj] = MFMA16(aL[fi], bH[fj], acc[fi][fj]);
      }
  };

  ldg(0);
  for (int kt = 0; kt < Dsz / 32; ++kt) {
    sts();
    __syncthreads();
    if (kt + 1 < Dsz / 32) ldg((kt + 1) * 32);
    mma();
    __syncthreads();
  }

  const int b = m0 >> 11;
  if (z < 2) {
    short* Oh = (z == 0) ? Qh : Kh;
    short* Ol = (z == 0) ? Ql : Kl;
#pragma unroll
    for (int fi = 0; fi < 4; ++fi)
#pragma unroll
      for (int fj = 0; fj < 4; ++fj) {
        const int nc = n0 + wn + fj * 16 + lr;
        const int hh = nc >> 6, dk = nc & 63;
#pragma unroll
        for (int r = 0; r < 4; ++r) {
          const int s = (m0 & 2047) + wm + fi * 16 + kg * 4 + r;
          const size_t addr = ((size_t)((b * Hsz + hh) * Ssz + s)) * DKsz + dk;
          float v = acc[fi][fj][r];
          short hv = f2bf(v);
          Oh[addr] = hv;
          Ol[addr] = f2bf(v - bf2f(hv));
        }
      }
  } else {
#pragma unroll
    for (int fi = 0; fi < 4; ++fi)
#pragma unroll
      for (int fj = 0; fj < 4; ++fj) {
        const int nc = n0 + wn + fj * 16 + lr;
        const int hh = nc >> 6, dk = nc & 63;
        const int s0 = (m0 & 2047) + wm + fi * 16 + kg * 4;
        bf16x4 hv, lv;
#pragma unroll
        for (int r = 0; r < 4; ++r) {
          float v = acc[fi][fj][r];
          short x = f2bf(v);
          hv[r] = x;
          lv[r] = f2bf(v - bf2f(x));
        }
        const size_t addr = ((size_t)(b * Hsz + hh) * DKsz + dk) * Ssz + s0;
        *(bf16x4*)(Vth + addr) = hv;
        *(bf16x4*)(Vtl + addr) = lv;
      }
  }
}

// ---------------------------------------------------------------------------
// Kernel 2: scores = Q*K^T * 0.125 per (b,h), raw fp32 into attn region.
// ---------------------------------------------------------------------------
__global__ __launch_bounds__(256, 2) void scores_k(
    const short* __restrict__ Qh, const short* __restrict__ Ql,
    const short* __restrict__ Kh, const short* __restrict__ Kl,
    float* __restrict__ attn) {
  const int bh = blockIdx.z;
  __shared__ __align__(16) short Ah[128][40];
  __shared__ __align__(16) short Al[128][40];
  __shared__ __align__(16) short Bh[128][40];
  __shared__ __align__(16) short Bl[128][40];

  const int t = threadIdx.x;
  const int l = t & 63, wid = t >> 6;
  const int wm = (wid >> 1) * 64, wn = (wid & 1) * 64;
  const int lr = l & 15, kg = l >> 4;
  const int m0 = blockIdx.y * 128, n0 = blockIdx.x * 128;
  const int sr = t >> 2, sc = (t & 3) * 8;  // 64 rows x (4thr*8col)

  const size_t base = (size_t)bh * Ssz * DKsz;
  const short* Qhb = Qh + base;
  const short* Qlb = Ql + base;
  const short* Khb = Kh + base;
  const short* Klb = Kl + base;

  f32x4 acc[4][4] = {};
  bf16x8 qh[2], ql4[2], kh[2], kl4[2];

  auto ldg = [&](int k0) {
#pragma unroll
    for (int i = 0; i < 2; ++i) {
      qh[i] = *(const bf16x8*)(Qhb + (size_t)(m0 + sr + i * 64) * DKsz + k0 + sc);
      ql4[i] = *(const bf16x8*)(Qlb + (size_t)(m0 + sr + i * 64) * DKsz + k0 + sc);
      kh[i] = *(const bf16x8*)(Khb + (size_t)(n0 + sr + i * 64) * DKsz + k0 + sc);
      kl4[i] = *(const bf16x8*)(Klb + (size_t)(n0 + sr + i * 64) * DKsz + k0 + sc);
    }
  };
  auto sts = [&]() {
#pragma unroll
    for (int i = 0; i < 2; ++i) {
      *(bf16x8*)&Ah[sr + i * 64][sc] = qh[i];
      *(bf16x8*)&Al[sr + i * 64][sc] = ql4[i];
      *(bf16x8*)&Bh[sr + i * 64][sc] = kh[i];
      *(bf16x8*)&Bl[sr + i * 64][sc] = kl4[i];
    }
  };
  auto mma = [&]() {
    bf16x8 aH[4], aL[4], bH[4], bL[4];
#pragma unroll
    for (int f = 0; f < 4; ++f) {
      aH[f] = *(const bf16x8*)&Ah[wm + f * 16 + lr][kg * 8];
      aL[f] = *(const bf16x8*)&Al[wm + f * 16 + lr][kg * 8];
      bH[f] = *(const bf16x8*)&Bh[wn + f * 16 + lr][kg * 8];
      bL[f] = *(const bf16x8*)&Bl[wn + f * 16 + lr][kg * 8];
    }
#pragma unroll
    for (int fi = 0; fi < 4; ++fi)
#pragma unroll
      for (int fj = 0; fj < 4; ++fj) {
        acc[fi][fj] = MFMA16(aH[fi], bH[fj], acc[fi][fj]);
        acc[fi][fj] = MFMA16(aH[fi], bL[fj], acc[fi][fj]);
        acc[fi][fj] = MFMA16(aL[fi], bH[fj], acc[fi][fj]);
      }
  };

  ldg(0);
  for (int kt = 0; kt < 2; ++kt) {
    sts();
    __syncthreads();
    if (kt == 0) ldg(32);
    mma();
    __syncthreads();
  }

  float* Ab = attn + (size_t)bh * Ssz * Ssz;
#pragma unroll
  for (int fi = 0; fi < 4; ++fi)
#pragma unroll
    for (int fj = 0; fj < 4; ++fj) {
      const int q = m0 + wm + fi * 16 + kg * 4;
      const int c = n0 + wn + fj * 16 + lr;
#pragma unroll
      for (int r = 0; r < 4; ++r)
        Ab[(size_t)(q + r) * Ssz + c] = acc[fi][fj][r] * 0.125f;
    }
}

// ---------------------------------------------------------------------------
// Kernel 3: row softmax in place (unchanged from fp32 baseline).
// ---------------------------------------------------------------------------
__global__ __launch_bounds__(256) void softmax_k(float* __restrict__ attn) {
  float* p = attn + (size_t)blockIdx.x * Ssz;
  const int t = threadIdx.x;
  float4 v0 = ((const float4*)p)[t];
  float4 v1 = ((const float4*)p)[t + 256];

  float mx = fmaxf(fmaxf(fmaxf(v0.x, v0.y), fmaxf(v0.z, v0.w)),
                   fmaxf(fmaxf(v1.x, v1.y), fmaxf(v1.z, v1.w)));
  __shared__ float red[256];
  red[t] = mx;
  __syncthreads();
  for (int o = 128; o > 0; o >>= 1) {
    if (t < o) red[t] = fmaxf(red[t], red[t + o]);
    __syncthreads();
  }
  const float rmax = red[0];
  __syncthreads();

  v0.x = __expf(v0.x - rmax); v0.y = __expf(v0.y - rmax);
  v0.z = __expf(v0.z - rmax); v0.w = __expf(v0.w - rmax);
  v1.x = __expf(v1.x - rmax); v1.y = __expf(v1.y - rmax);
  v1.z = __expf(v1.z - rmax); v1.w = __expf(v1.w - rmax);
  float sm = (v0.x + v0.y + v0.z + v0.w) + (v1.x + v1.y + v1.z + v1.w);
  red[t] = sm;
  __syncthreads();
  for (int o = 128; o > 0; o >>= 1) {
    if (t < o) red[t] += red[t + o];
    __syncthreads();
  }
  const float inv = 1.0f / red[0];

  v0.x *= inv; v0.y *= inv; v0.z *= inv; v0.w *= inv;
  v1.x *= inv; v1.y *= inv; v1.z *= inv; v1.w *= inv;
  ((float4*)p)[t] = v0;
  ((float4*)p)[t + 256] = v1;
}

// ---------------------------------------------------------------------------
// Kernel 4: ctx = attn * V per (b,h).  BM=128, BN=64 (one head), BK=32.
// attn fp32 split on the fly; V comes pre-transposed [bh][dk][s].
// Writes split-bf16 ctx in merged [b,s,D] layout.
// ---------------------------------------------------------------------------
__global__ __launch_bounds__(256, 2) void ctx_k(
    const float* __restrict__ attn, const short* __restrict__ Vth,
    const short* __restrict__ Vtl, short* __restrict__ Ch,
    short* __restrict__ Cl) {
  const int bh = blockIdx.y;
  const int m0 = blockIdx.x * 128;
  __shared__ __align__(16) short Ah[128][40];
  __shared__ __align__(16) short Al[128][40];
  __shared__ __align__(16) short Bh[64][40];
  __shared__ __align__(16) short Bl[64][40];

  const int t = threadIdx.x;
  const int l = t & 63, wid = t >> 6;
  const int wm = (wid >> 1) * 64, wn = (wid & 1) * 32;
  const int lr = l & 15, kg = l >> 4;
  const int sra = t >> 3, sca = (t & 7) * 4;
  const int srb = t >> 2, scb = (t & 3) * 8;

  const float* Ag = attn + (size_t)bh * Ssz * Ssz;
  const short* Vhb = Vth + (size_t)bh * DKsz * Ssz;
  const short* Vlb = Vtl + (size_t)bh * DKsz * Ssz;

  f32x4 acc[4][2] = {};
  float4 av[4];
  bf16x8 vh, vl;

  auto ldg = [&](int k0) {
#pragma unroll
    for (int i = 0; i < 4; ++i)
      av[i] = *(const float4*)(Ag + (size_t)(m0 + sra + i * 32) * Ssz + k0 + sca);
    vh = *(const bf16x8*)(Vhb + (size_t)srb * Ssz + k0 + scb);
    vl = *(const bf16x8*)(Vlb + (size_t)srb * Ssz + k0 + scb);
  };
  auto sts = [&]() {
#pragma unroll
    for (int i = 0; i < 4; ++i) {
      bf16x4 hv, lv;
      const float* pa = (const float*)&av[i];
#pragma unroll
      for (int j = 0; j < 4; ++j) {
        float f = pa[j];
        short h = f2bf(f);
        hv[j] = h;
        lv[j] = f2bf(f - bf2f(h));
      }
      *(bf16x4*)&Ah[sra + i * 32][sca] = hv;
      *(bf16x4*)&Al[sra + i * 32][sca] = lv;
    }
    *(bf16x8*)&Bh[srb][scb] = vh;
    *(bf16x8*)&Bl[srb][scb] = vl;
  };
  auto mma = [&]() {
    bf16x8 aH[4], aL[4], bH[2], bL[2];
#pragma unroll
    for (int f = 0; f < 4; ++f) {
      aH[f] = *(const bf16x8*)&Ah[wm + f * 16 + lr][kg * 8];
      aL[f] = *(const bf16x8*)&Al[wm + f * 16 + lr][kg * 8];
    }
#pragma unroll
    for (int f = 0; f < 2; ++f) {
      bH[f] = *(const bf16x8*)&Bh[wn + f * 16 + lr][kg * 8];
      bL[f] = *(const bf16x8*)&Bl[wn + f * 16 + lr][kg * 8];
    }
#pragma unroll
    for (int fi = 0; fi < 4; ++fi)
#pragma unroll
      for (int fj = 0; fj < 2; ++fj) {
        acc[fi][fj] = MFMA16(aH[fi], bH[fj], acc[fi][fj]);
        acc[fi][fj] = MFMA16(aH[fi], bL[fj], acc[fi][fj]);
        acc[fi][fj] = MFMA16(aL[fi], bH[fj], acc[fi][fj]);
      }
  };

  ldg(0);
  for (int kt = 0; kt < Ssz / 32; ++kt) {
    sts();
    __syncthreads();
    if (kt + 1 < Ssz / 32) ldg((kt + 1) * 32);
    mma();
    __syncthreads();
  }

  const int b = bh >> 4, hh = bh & 15;
#pragma unroll
  for (int fi = 0; fi < 4; ++fi)
#pragma unroll
    for (int fj = 0; fj < 2; ++fj) {
      const int n = wn + fj * 16 + lr;
      const int s0 = m0 + wm + fi * 16 + kg * 4;
#pragma unroll
      for (int r = 0; r < 4; ++r) {
        float v = acc[fi][fj][r];
        short h = f2bf(v);
        const size_t addr = ((size_t)(b * Ssz + s0 + r)) * Dsz + hh * DKsz + n;
        Ch[addr] = h;
        Cl[addr] = f2bf(v - bf2f(h));
      }
    }
}

// ---------------------------------------------------------------------------
// Kernel 5: out = ctx * Wo^T.  A split-bf16 from workspace, B fp32 split on fly.
// ---------------------------------------------------------------------------
__global__ __launch_bounds__(256, 2) void out_proj_k(
    const short* __restrict__ Ch, const short* __restrict__ Cl,
    const float* __restrict__ Wo, float* __restrict__ out) {
  __shared__ __align__(16) short Ah[128][40];
  __shared__ __align__(16) short Al[128][40];
  __shared__ __align__(16) short Bh[128][40];
  __shared__ __align__(16) short Bl[128][40];

  const int t = threadIdx.x;
  const int l = t & 63, wid = t >> 6;
  const int wm = (wid >> 1) * 64, wn = (wid & 1) * 64;
  const int lr = l & 15, kg = l >> 4;
  const int m0 = blockIdx.y * 128, n0 = blockIdx.x * 128;
  const int sra = t >> 2, sca = (t & 3) * 8;  // A (bf16)
  const int srb = t >> 3, scb = (t & 7) * 4;  // B (fp32)

  f32x4 acc[4][4] = {};
  bf16x8 ahr[2], alr[2];
  float4 bv[4];

  auto ldg = [&](int k0) {
#pragma unroll
    for (int i = 0; i < 2; ++i) {
      ahr[i] = *(const bf16x8*)(Ch + (size_t)(m0 + sra + i * 64) * Dsz + k0 + sca);
      alr[i] = *(const bf16x8*)(Cl + (size_t)(m0 + sra + i * 64) * Dsz + k0 + sca);
    }
#pragma unroll
    for (int i = 0; i < 4; ++i)
      bv[i] = *(const float4*)(Wo + (size_t)(n0 + srb + i * 32) * Dsz + k0 + scb);
  };
  auto sts = [&]() {
#pragma unroll
    for (int i = 0; i < 2; ++i) {
      *(bf16x8*)&Ah[sra + i * 64][sca] = ahr[i];
      *(bf16x8*)&Al[sra + i * 64][sca] = alr[i];
    }
#pragma unroll
    for (int i = 0; i < 4; ++i) {
      bf16x4 hv, lv;
      const float* pb = (const float*)&bv[i];
#pragma unroll
      for (int j = 0; j < 4; ++j) {
        float f = pb[j];
        short h = f2bf(f);
        hv[j] = h;
        lv[j] = f2bf(f - bf2f(h));
      }
      *(bf16x4*)&Bh[srb + i * 32][scb] = hv;
      *(bf16x4*)&Bl[srb + i * 32][scb] = lv;
    }
  };
  auto mma = [&]() {
    bf16x8 aH[4], aL[4], bH[4], bL[4];
#pragma unroll
    for (int f = 0; f < 4; ++f) {
      aH[f] = *(const bf16x8*)&Ah[wm + f * 16 + lr][kg * 8];
      aL[f] = *(const bf16x8*)&Al[wm + f * 16 + lr][kg * 8];
      bH[f] = *(const bf16x8*)&Bh[wn + f * 16 + lr][kg * 8];
      bL[f] = *(const bf16x8*)&Bl[wn + f * 16 + lr][kg * 8];
    }
#pragma unroll
    for (int fi = 0; fi < 4; ++fi)
#pragma unroll
      for (int fj = 0; fj < 4; ++fj) {
        acc[fi][fj] = MFMA16(aH[fi], bH[fj], acc[fi][fj]);
        acc[fi][fj] = MFMA16(aH[fi], bL[fj], acc[fi][fj]);
        acc[fi][fj] = MFMA16(aL[fi], bH[fj], acc[fi][fj]);
      }
  };

  ldg(0);
  for (int kt = 0; kt < Dsz / 32; ++kt) {
    sts();
    __syncthreads();
    if (kt + 1 < Dsz / 32) ldg((kt + 1) * 32);
    mma();
    __syncthreads();
  }

#pragma unroll
  for (int fi = 0; fi < 4; ++fi)
#pragma unroll
    for (int fj = 0; fj < 4; ++fj) {
      const int q = m0 + wm + fi * 16 + kg * 4;
      const int c = n0 + wn + fj * 16 + lr;
#pragma unroll
      for (int r = 0; r < 4; ++r)
        out[(size_t)(q + r) * Dsz + c] = acc[fi][fj][r];
    }
}

extern "C" void kernel_launch(void* const* d_in, const int* in_sizes, int n_in,
                              void* d_out, int out_size, void* d_ws,
                              size_t ws_size, hipStream_t stream) {
  const float* Xq = (const float*)d_in[0];
  const float* Xk = (const float*)d_in[1];
  const float* Xv = (const float*)d_in[2];
  const float* Wq = (const float*)d_in[3];
  const float* Wk = (const float*)d_in[4];
  const float* Wv = (const float*)d_in[5];
  const float* Wo = (const float*)d_in[6];

  float* out = (float*)d_out;             // [B,S,D]
  float* attn = out + (size_t)Msz * Dsz;  // [B,H,S,S]

  // Workspace: 8 split-bf16 tensors x 4M elems x 2B = 64 MB total.
  const size_t NQ = (size_t)BHsz * Ssz * DKsz;  // 4,194,304
  short* Qh = (short*)d_ws;
  short* Ql = Qh + NQ;
  short* Kh = Ql + NQ;
  short* Kl = Kh + NQ;
  short* Vth = Kl + NQ;
  short* Vtl = Vth + NQ;
  short* Ch = Vtl + NQ;   // ctx split, [B,S,D] merged: same elem count
  short* Cl = Ch + NQ;

  qkv_proj_k<<<dim3(8, 32, 3), 256, 0, stream>>>(Xq, Xk, Xv, Wq, Wk, Wv,
                                                 Qh, Ql, Kh, Kl, Vth, Vtl);
  scores_k<<<dim3(16, 16, 32), 256, 0, stream>>>(Qh, Ql, Kh, Kl, attn);
  softmax_k<<<dim3(65536, 1, 1), 256, 0, stream>>>(attn);
  ctx_k<<<dim3(16, 32, 1), 256, 0, stream>>>(attn, Vth, Vtl, Ch, Cl);
  out_proj_k<<<dim3(8, 32, 1), 256, 0, stream>>>(Ch, Cl, Wo, out);
}